// Round 7
// baseline (483.472 us; speedup 1.0000x reference)
//
#include <hip/hip_runtime.h>
#include <hip/hip_bf16.h>
#include <math.h>

// Problem constants
#define BATCH 4
#define SEQ 2048
#define FEAT 1024
#define HEADS 16
#define HDIM 64
#define FF 500
#define FFP 512                 // FF padded to multiple of 128
#define ROWS (BATCH * SEQ)      // 8192
#define QKVSTR 3072             // fused q|k|v logical N
#define QKSTR 2048              // packed q|k row stride (V split out)
#define AQ 128                  // attn q-rows per block

typedef unsigned short ushortT;
typedef __attribute__((ext_vector_type(8))) short short8;   // 8 bf16 (4 VGPRs)
typedef __attribute__((ext_vector_type(4))) float floatx4;  // MFMA acc

#if defined(__has_builtin) && __has_builtin(__builtin_amdgcn_exp2f)
#define EXP2F(x) __builtin_amdgcn_exp2f(x)
#else
#define EXP2F(x) exp2f(x)
#endif

__device__ __forceinline__ unsigned short f2bf(float f) {
    unsigned int u = __builtin_bit_cast(unsigned int, f);
    u += 0x7fffu + ((u >> 16) & 1u);           // RNE
    return (unsigned short)(u >> 16);
}
__device__ __forceinline__ float bf2f(short b) {
    unsigned int u = ((unsigned int)(unsigned short)b) << 16;
    return __builtin_bit_cast(float, u);
}

__device__ __forceinline__ void async16(void* lds, const void* g) {
    __builtin_amdgcn_global_load_lds(
        (const __attribute__((address_space(1))) unsigned int*)g,
        (__attribute__((address_space(3))) unsigned int*)lds, 16, 0, 0);
}

// ---------------------------------------------------------------------------
// Unified prep: 6 weight transpose+convert tiles + bias concat/pad.
// ---------------------------------------------------------------------------
__global__ void prep_kernel(const float* __restrict__ Wq, const float* __restrict__ Wk,
                            const float* __restrict__ Wv, const float* __restrict__ Wo,
                            const float* __restrict__ W1, const float* __restrict__ W2,
                            const float* __restrict__ bq, const float* __restrict__ bk,
                            const float* __restrict__ bv, const float* __restrict__ b1,
                            ushortT* __restrict__ Wqkvt, ushortT* __restrict__ Wot,
                            ushortT* __restrict__ W1t, ushortT* __restrict__ W2t,
                            float* __restrict__ bqkv, float* __restrict__ b1p)
{
    const int t = blockIdx.x;
    const int tid = threadIdx.x;
    if (t == 1280) {
        for (int i = tid; i < QKVSTR; i += 256)
            bqkv[i] = (i < 1024) ? bq[i] : ((i < 2048) ? bk[i - 1024] : bv[i - 2048]);
        for (int i = tid; i < FFP; i += 256)
            b1p[i] = (i < FF) ? b1[i] : 0.0f;
        return;
    }
    const float* W; ushortT* Wt; int K, N, Kp, bx, by;
    if (t < 1024) {
        const int wi = t >> 8, lt = t & 255;
        bx = lt & 15; by = lt >> 4; K = FEAT; N = FEAT; Kp = FEAT;
        W  = (wi == 0) ? Wq : (wi == 1) ? Wk : (wi == 2) ? Wv : Wo;
        Wt = (wi == 3) ? Wot : (Wqkvt + (size_t)wi * FEAT * FEAT);
    } else if (t < 1152) {
        const int lt = t - 1024; bx = lt & 7; by = lt >> 3;
        K = FEAT; N = FF; Kp = FEAT; W = W1; Wt = W1t;
    } else {
        const int lt = t - 1152; bx = lt & 15; by = lt >> 4;
        K = FF; N = FEAT; Kp = FFP; W = W2; Wt = W2t;
    }

    __shared__ float T[64][65];
    const int n0 = bx * 64, k0 = by * 64;
    const int r = tid >> 4;
    const int c = (tid & 15) * 4;
    #pragma unroll
    for (int i = 0; i < 4; i++) {
        const int kk = k0 + r + i * 16;
        #pragma unroll
        for (int e = 0; e < 4; e++) {
            const int nn = n0 + c + e;
            T[r + i * 16][c + e] = (kk < K && nn < N) ? W[(size_t)kk * N + nn] : 0.0f;
        }
    }
    __syncthreads();
    #pragma unroll
    for (int i = 0; i < 4; i++) {
        const int nn = r + i * 16;
        ushort4 o;
        o.x = f2bf(T[c + 0][nn]);
        o.y = f2bf(T[c + 1][nn]);
        o.z = f2bf(T[c + 2][nn]);
        o.w = f2bf(T[c + 3][nn]);
        *(ushort4*)(Wt + (size_t)(n0 + nn) * Kp + k0 + c) = o;
    }
}

// ---------------------------------------------------------------------------
// Mask bit-pack: int32 0/1 [B,S,S] -> bitmask dwords [B,S,S/32].
// ---------------------------------------------------------------------------
__global__ void maskbits_kernel(const int* __restrict__ mask,
                                unsigned int* __restrict__ bits)
{
    const size_t g = (size_t)blockIdx.x * 256 + threadIdx.x;
    const int lane = threadIdx.x & 63;
    const unsigned long long bal = __ballot(mask[g] != 0);
    if (lane == 0)  bits[g >> 5] = (unsigned int)bal;
    if (lane == 32) bits[g >> 5] = (unsigned int)(bal >> 32);
}

// ---------------------------------------------------------------------------
// LayerNorm -> bf16. One block per row; wave-shuffle reduction, 1 barrier.
// ---------------------------------------------------------------------------
__global__ void ln_kernel(const float* __restrict__ x,
                          const float* __restrict__ alpha,
                          const float* __restrict__ bias,
                          ushortT* __restrict__ out)
{
    __shared__ float p1[4], p2[4];
    const int row = blockIdx.x;
    const int tid = threadIdx.x;
    const int wave = tid >> 6, lane = tid & 63;
    float4 v = ((const float4*)(x + (size_t)row * FEAT))[tid];

    float s1 = v.x + v.y + v.z + v.w;
    float s2 = v.x * v.x + v.y * v.y + v.z * v.z + v.w * v.w;
    #pragma unroll
    for (int off = 32; off > 0; off >>= 1) {
        s1 += __shfl_xor(s1, off);
        s2 += __shfl_xor(s2, off);
    }
    if (lane == 0) { p1[wave] = s1; p2[wave] = s2; }
    __syncthreads();
    const float t1 = p1[0] + p1[1] + p1[2] + p1[3];
    const float t2 = p2[0] + p2[1] + p2[2] + p2[3];
    const float mean = t1 * (1.0f / 1024.0f);
    const float var = fmaxf(t2 - 1024.0f * mean * mean, 0.0f) * (1.0f / 1023.0f);
    const float inv = 1.0f / (sqrtf(var) + 1e-6f);

    const float4 a = ((const float4*)alpha)[tid];
    const float4 b = ((const float4*)bias)[tid];
    ushort4 o;
    o.x = f2bf(a.x * (v.x - mean) * inv + b.x);
    o.y = f2bf(a.y * (v.y - mean) * inv + b.y);
    o.z = f2bf(a.z * (v.z - mean) * inv + b.z);
    o.w = f2bf(a.w * (v.w - mean) * inv + b.w);
    ((ushort4*)(out + (size_t)row * FEAT))[tid] = o;
}

// ---------------------------------------------------------------------------
// bf16 MFMA GEMM, BK=64 (two 32-K planes, 64B LDS rows), 128xBN tiles.
// 1D grid with XCD-aware swizzle: xcd = id&7 owns an N-column panel (TNX/8
// column-tiles -> Bt panel fits per-XCD L2); consecutive per-XCD blocks share
// the same A row-panel. SPLITV: cols>=2048 (V) written transposed into vt
// [b][h][d][j]; q|k written packed at stride 2048.
// ---------------------------------------------------------------------------
template<int ACT, int RES, int OUT_BF16, int BN, int TNX, int SPLITV>
__global__ __launch_bounds__(256)
void mfma_gemm(const ushortT* __restrict__ A, const ushortT* __restrict__ Bt,
               const float* __restrict__ bias, const float* __restrict__ R,
               void* __restrict__ Cout, ushortT* __restrict__ vtout,
               int M, int N, int K)
{
    constexpr int MT = (BN == 128) ? 4 : 2;
    constexpr int MSPAN = (BN == 128) ? 64 : 32;
    constexpr int CPX = TNX >> 3;            // column-tiles per XCD
    __shared__ ushortT As[2][128 * 32];
    __shared__ ushortT Bs[2][BN * 32];

    const int tid  = threadIdx.x;
    const int wave = tid >> 6, lane = tid & 63;
    const int quad = lane >> 4, l16 = lane & 15;
    const int wm = (BN == 128) ? (wave >> 1) : wave;
    const int wn = (BN == 128) ? (wave & 1) : 0;

    const int id = blockIdx.x;
    const int xcd = id & 7, s = id >> 3;
    const int bx = xcd * CPX + (s % CPX);
    const int by = s / CPX;
    const int row0 = by * 128, col0 = bx * BN;

    const floatx4 z4 = {0.f, 0.f, 0.f, 0.f};
    floatx4 acc[MT][4];
    #pragma unroll
    for (int i = 0; i < MT; i++)
        #pragma unroll
        for (int j = 0; j < 4; j++) acc[i][j] = z4;

    for (int k0 = 0; k0 < K; k0 += 64) {
        __syncthreads();
        #pragma unroll
        for (int kh = 0; kh < 2; kh++) {
            #pragma unroll
            for (int i = 0; i < 2; i++) {
                const int rbase = 16 * (wave + 4 * i);
                const int r = rbase + (lane >> 2);
                const int co = (lane & 3) * 8;
                async16((char*)As[kh] + rbase * 64,
                        A + (size_t)(row0 + r) * K + k0 + kh * 32 + co);
            }
            if (BN == 128) {
                #pragma unroll
                for (int i = 0; i < 2; i++) {
                    const int rbase = 16 * (wave + 4 * i);
                    const int r = rbase + (lane >> 2);
                    const int co = (lane & 3) * 8;
                    async16((char*)Bs[kh] + rbase * 64,
                            Bt + (size_t)(col0 + r) * K + k0 + kh * 32 + co);
                }
            } else {
                const int rbase = 16 * wave;
                const int r = rbase + (lane >> 2);
                const int co = (lane & 3) * 8;
                async16((char*)Bs[kh] + rbase * 64,
                        Bt + (size_t)(col0 + r) * K + k0 + kh * 32 + co);
            }
        }
        __syncthreads();

        #pragma unroll
        for (int kh = 0; kh < 2; kh++) {
            short8 af[MT], bf[4];
            #pragma unroll
            for (int mt = 0; mt < MT; mt++)
                af[mt] = *(const short8*)&As[kh][(MSPAN * wm + 16 * mt + l16) * 32 + quad * 8];
            #pragma unroll
            for (int nt = 0; nt < 4; nt++)
                bf[nt] = *(const short8*)&Bs[kh][(64 * wn + 16 * nt + l16) * 32 + quad * 8];
            #pragma unroll
            for (int mt = 0; mt < MT; mt++)
                #pragma unroll
                for (int nt = 0; nt < 4; nt++)
                    acc[mt][nt] = __builtin_amdgcn_mfma_f32_16x16x32_bf16(
                        af[mt], bf[nt], acc[mt][nt], 0, 0, 0);
        }
    }

    if (SPLITV && col0 >= 2048) {
        // V block: write transposed into vt[((b*16+h)*64+d)*SEQ + j]
        #pragma unroll
        for (int mt = 0; mt < MT; mt++) {
            const int row = row0 + MSPAN * wm + 16 * mt + quad * 4;  // 4 consec rows
            const int b = row >> 11, j = row & (SEQ - 1);
            #pragma unroll
            for (int nt = 0; nt < 4; nt++) {
                const int col = col0 + 64 * wn + 16 * nt + l16;
                const int cv = col - 2048;
                const int h = cv >> 6, d = cv & 63;
                const float bb = bias[col];
                ushort4 o;
                o.x = f2bf(acc[mt][nt][0] + bb);
                o.y = f2bf(acc[mt][nt][1] + bb);
                o.z = f2bf(acc[mt][nt][2] + bb);
                o.w = f2bf(acc[mt][nt][3] + bb);
                *(ushort4*)(vtout + ((size_t)((b * HEADS + h) * 64 + d)) * SEQ + j) = o;
            }
        }
        return;
    }

    const int cn = SPLITV ? QKSTR : N;   // dest row stride
    #pragma unroll
    for (int mt = 0; mt < MT; mt++) {
        #pragma unroll
        for (int nt = 0; nt < 4; nt++) {
            const int col = col0 + 64 * wn + 16 * nt + l16;
            #pragma unroll
            for (int r = 0; r < 4; r++) {
                const int row = row0 + MSPAN * wm + 16 * mt + quad * 4 + r;
                float val = acc[mt][nt][r] + bias[col];
                if (ACT == 1) val = (val > 0.0f) ? val : (__expf(val) - 1.0f);
                if (RES) val += R[(size_t)row * N + col];
                if (OUT_BF16)
                    ((ushortT*)Cout)[(size_t)row * cn + col] = f2bf(val);
                else
                    ((float*)Cout)[(size_t)row * cn + col] = val;
            }
        }
    }
}

// ---------------------------------------------------------------------------
// MFMA flash attention: 128 q-rows/block, 64-j tiles, no-max softmax, S^T
// form. Single-buffer K/V in LDS (32 KB total -> 5 blocks/CU capacity; grid
// 1024 = 4/CU fully resident, no tail). Register prefetch of next tile; two
// barriers/iter (B-end separates last V-read from V-write). Q pre-scaled by
// log2(e)/8, p=exp2(s); masked -> 1.0. Row sums via ones-MFMA.
// ---------------------------------------------------------------------------
__global__ __launch_bounds__(256)
void mfma_attn(const ushortT* __restrict__ qk, const ushortT* __restrict__ vt,
               const unsigned int* __restrict__ mbits, ushortT* __restrict__ attn_out)
{
    __shared__ ushortT Ks[64 * 64];    // [j][d] swizzled
    __shared__ ushortT Vts[64 * 64];   // [d][j] swizzled
    __shared__ ushortT Ps[AQ * 64];    // [m][j] swizzled, wave-private rows

    const int tid = threadIdx.x;
    const int wave = tid >> 6, lane = tid & 63;
    const int quad = lane >> 4, l16 = lane & 15;
    const int bid = blockIdx.x;
    const int qt = bid & 15, h = (bid >> 4) & 15, b = bid >> 8;
    const int q0 = qt * AQ;

    const ushortT* qptr = qk;
    const ushortT* kptr = qk + 1024;

    // Q fragments for both m-groups, pre-scaled by log2(e)/8.
    short8 qf[2][2];
    #pragma unroll
    for (int mg = 0; mg < 2; mg++) {
        const size_t qrow = (size_t)(b * SEQ + q0 + 32 * wave + mg * 16 + l16);
        short8 t0 = *(const short8*)(qptr + qrow * QKSTR + h * 64 + quad * 8);
        short8 t1 = *(const short8*)(qptr + qrow * QKSTR + h * 64 + 32 + quad * 8);
        const float cs = 0.125f * 1.4426950408889634f;
        #pragma unroll
        for (int i = 0; i < 8; i++) {
            qf[mg][0][i] = (short)f2bf(bf2f(t0[i]) * cs);
            qf[mg][1][i] = (short)f2bf(bf2f(t1[i]) * cs);
        }
    }

    short8 ones8;
    #pragma unroll
    for (int i = 0; i < 8; i++) ones8[i] = (short)0x3F80;  // bf16 1.0

    const floatx4 z4 = {0.f, 0.f, 0.f, 0.f};
    floatx4 o[2][4];
    #pragma unroll
    for (int mg = 0; mg < 2; mg++)
        #pragma unroll
        for (int dt = 0; dt < 4; dt++) o[mg][dt] = z4;
    floatx4 lacc[2] = {z4, z4};

    // staging pointers (advance per tile)
    const int rr = tid >> 2;
    const int c0 = (tid & 3) * 2;
    const ushortT* gk = kptr + (size_t)(b * SEQ + rr) * QKSTR + h * 64;
    const ushortT* gv = vt + ((size_t)((b * HEADS + h) * 64 + rr)) * SEQ;
    short8 rk0, rk1, rv0, rv1;

#define ATTN_ISSUE() {                                                       \
    rk0 = *(const short8*)(gk + c0 * 8);                                     \
    rk1 = *(const short8*)(gk + c0 * 8 + 8);                                 \
    rv0 = *(const short8*)(gv + c0 * 8);                                     \
    rv1 = *(const short8*)(gv + c0 * 8 + 8);                                 \
    gk += (size_t)64 * QKSTR; gv += 64; }

#define ATTN_WRITE() {                                                       \
    *(short8*)&Ks[rr * 64 + ((c0 ^ (rr & 7)) * 8)] = rk0;                    \
    *(short8*)&Ks[rr * 64 + (((c0 + 1) ^ (rr & 7)) * 8)] = rk1;              \
    *(short8*)&Vts[rr * 64 + ((c0 ^ (rr & 7)) * 8)] = rv0;                   \
    *(short8*)&Vts[rr * 64 + (((c0 + 1) ^ (rr & 7)) * 8)] = rv1; }

    const unsigned int* mrowp[2];
    mrowp[0] = mbits + (size_t)(b * SEQ + q0 + 32 * wave + l16) * (SEQ / 32);
    mrowp[1] = mrowp[0] + 16 * (SEQ / 32);
    const int mloc0 = 32 * wave + l16;

    // Prologue: stage tile 0
    ATTN_ISSUE();
    ATTN_WRITE();

    for (int jt = 0; jt < 32; jt++) {
        __syncthreads();                       // K/V writes visible
        unsigned int w[2][2];
        #pragma unroll
        for (int mg = 0; mg < 2; mg++) {
            w[mg][0] = mrowp[mg][jt * 2];
            w[mg][1] = mrowp[mg][jt * 2 + 1];
        }
        if (jt < 31) ATTN_ISSUE();             // prefetch next tile into regs

        // S^T = K @ Q^T for both m-groups (K frags read once)
        floatx4 st[2][4];
        #pragma unroll
        for (int nt = 0; nt < 4; nt++) {
            const int j = nt * 16 + l16;
            short8 ka0 = *(const short8*)&Ks[j * 64 + ((quad ^ (j & 7)) * 8)];
            short8 ka1 = *(const short8*)&Ks[j * 64 + (((4 + quad) ^ (j & 7)) * 8)];
            #pragma unroll
            for (int mg = 0; mg < 2; mg++) {
                floatx4 t = z4;
                t = __builtin_amdgcn_mfma_f32_16x16x32_bf16(ka0, qf[mg][0], t, 0, 0, 0);
                t = __builtin_amdgcn_mfma_f32_16x16x32_bf16(ka1, qf[mg][1], t, 0, 0, 0);
                st[mg][nt] = t;
            }
        }

        // softmax: p = exp2(masked ? 0 : s); packed bf16 writes into Ps[m][j]
        #pragma unroll
        for (int mg = 0; mg < 2; mg++) {
            const int mloc = mloc0 + mg * 16;
            #pragma unroll
            for (int nt = 0; nt < 4; nt++) {
                const unsigned int ww = (nt & 2) ? w[mg][1] : w[mg][0];
                const unsigned int wsh = ww >> ((nt & 1) * 16 + quad * 4);
                float p[4];
                p[0] = EXP2F((wsh & 1u) ? st[mg][nt][0] : 0.0f);
                p[1] = EXP2F((wsh & 2u) ? st[mg][nt][1] : 0.0f);
                p[2] = EXP2F((wsh & 4u) ? st[mg][nt][2] : 0.0f);
                p[3] = EXP2F((wsh & 8u) ? st[mg][nt][3] : 0.0f);
                const int j0 = nt * 16 + quad * 4;
                const int chunk = (j0 >> 3) ^ (mloc & 7);
                const int ci = j0 & 7;
                ushortT* dst = &Ps[mloc * 64 + chunk * 8 + ci];
                *(__hip_bfloat162*)(dst)     = __float22bfloat162_rn(make_float2(p[0], p[1]));
                *(__hip_bfloat162*)(dst + 2) = __float22bfloat162_rn(make_float2(p[2], p[3]));
            }
        }

        // O += P @ V ; lacc += P @ ones  (Ps rows wave-private: no barrier)
        short8 pa[2][2];
        #pragma unroll
        for (int mg = 0; mg < 2; mg++) {
            const int mloc = mloc0 + mg * 16;
            pa[mg][0] = *(const short8*)&Ps[mloc * 64 + ((quad ^ (mloc & 7)) * 8)];
            pa[mg][1] = *(const short8*)&Ps[mloc * 64 + (((4 + quad) ^ (mloc & 7)) * 8)];
            lacc[mg] = __builtin_amdgcn_mfma_f32_16x16x32_bf16(pa[mg][0], ones8, lacc[mg], 0, 0, 0);
            lacc[mg] = __builtin_amdgcn_mfma_f32_16x16x32_bf16(pa[mg][1], ones8, lacc[mg], 0, 0, 0);
        }
        #pragma unroll
        for (int dt = 0; dt < 4; dt++) {
            const int d = dt * 16 + l16;
            short8 vb0 = *(const short8*)&Vts[d * 64 + ((quad ^ (d & 7)) * 8)];
            short8 vb1 = *(const short8*)&Vts[d * 64 + (((4 + quad) ^ (d & 7)) * 8)];
            #pragma unroll
            for (int mg = 0; mg < 2; mg++) {
                o[mg][dt] = __builtin_amdgcn_mfma_f32_16x16x32_bf16(pa[mg][0], vb0, o[mg][dt], 0, 0, 0);
                o[mg][dt] = __builtin_amdgcn_mfma_f32_16x16x32_bf16(pa[mg][1], vb1, o[mg][dt], 0, 0, 0);
            }
        }

        __syncthreads();                       // all waves done reading K/V
        if (jt < 31) ATTN_WRITE();
    }

    // Normalize + store bf16.
    #pragma unroll
    for (int mg = 0; mg < 2; mg++) {
        #pragma unroll
        for (int r = 0; r < 4; r++) {
            const float inv_l = 1.0f / lacc[mg][r];
            const size_t row = (size_t)(b * SEQ + q0 + 32 * wave + mg * 16 + quad * 4 + r);
            #pragma unroll
            for (int dt = 0; dt < 4; dt++) {
                attn_out[row * FEAT + h * 64 + dt * 16 + l16] = f2bf(o[mg][dt][r] * inv_l);
            }
        }
    }
#undef ATTN_ISSUE
#undef ATTN_WRITE
}

// ---------------------------------------------------------------------------
// Launch
// ---------------------------------------------------------------------------
extern "C" void kernel_launch(void* const* d_in, const int* in_sizes, int n_in,
                              void* d_out, int out_size, void* d_ws, size_t ws_size,
                              hipStream_t stream)
{
    const float* x      = (const float*)d_in[0];
    const int*   mask   = (const int*)d_in[1];
    const float* alpha1 = (const float*)d_in[2];
    const float* bias1  = (const float*)d_in[3];
    const float* alpha2 = (const float*)d_in[4];
    const float* bias2  = (const float*)d_in[5];
    const float* Wq     = (const float*)d_in[6];
    const float* bq     = (const float*)d_in[7];
    const float* Wk     = (const float*)d_in[8];
    const float* bk     = (const float*)d_in[9];
    const float* Wv     = (const float*)d_in[10];
    const float* bv     = (const float*)d_in[11];
    const float* Wo     = (const float*)d_in[12];
    const float* bo     = (const float*)d_in[13];
    const float* W1     = (const float*)d_in[14];
    const float* b1     = (const float*)d_in[15];
    const float* W2     = (const float*)d_in[16];
    const float* b2     = (const float*)d_in[17];
    float* out = (float*)d_out;

    char* ws = (char*)d_ws;
    const size_t MB = 1024 * 1024;
    ushortT* x2b    = (ushortT*)(ws);              // LN1 out; attn out later
    ushortT* attn_o = (ushortT*)(ws);
    ushortT* qk     = (ushortT*)(ws + 16 * MB);    // packed q|k [8192][2048]
    ushortT* x2b2   = (ushortT*)(ws + 16 * MB);    // LN2 out (after attn)
    ushortT* hbuf   = (ushortT*)(ws + 32 * MB);    // FF hidden (after attn)
    ushortT* vtb    = (ushortT*)(ws + 48 * MB);    // 16 MB, v transposed
    ushortT* Wqkvt  = (ushortT*)(ws + 80 * MB);    // 6 MB  [3072][1024]
    ushortT* Wot    = (ushortT*)(ws + 86 * MB);    // 2 MB
    ushortT* W1t    = (ushortT*)(ws + 88 * MB);    // 1 MB  [512][1024]
    ushortT* W2t    = (ushortT*)(ws + 89 * MB);    // 1 MB  [1024][512]
    float*   b1p    = (float*)  (ws + 90 * MB);
    float*   bqkv   = (float*)  (ws + 90 * MB + 16384);
    unsigned int* mbits = (unsigned int*)(ws + 91 * MB); // 2 MB

    const dim3 blk(256);

    // Prep (1 launch) + mask pack
    prep_kernel<<<1281, blk, 0, stream>>>(Wq, Wk, Wv, Wo, W1, W2, bq, bk, bv, b1,
                                          Wqkvt, Wot, W1t, W2t, bqkv, b1p);
    maskbits_kernel<<<(BATCH * SEQ * SEQ) / 256, blk, 0, stream>>>(mask, mbits);

    // 1. LN1 -> bf16
    ln_kernel<<<ROWS, blk, 0, stream>>>(x, alpha1, bias1, x2b);

    // 2. Fused QKV projection; V written directly transposed (SPLITV)
    mfma_gemm<0, 0, 1, 128, 24, 1><<<1536, blk, 0, stream>>>(
        x2b, Wqkvt, bqkv, nullptr, qk, vtb, ROWS, QKVSTR, FEAT);

    // 3. Flash attention
    mfma_attn<<<BATCH * HEADS * (SEQ / AQ), blk, 0, stream>>>(qk, vtb, mbits, attn_o);

    // 4. out = x + attn @ Wo + bo
    mfma_gemm<0, 1, 0, 128, 8, 0><<<512, blk, 0, stream>>>(
        attn_o, Wot, bo, x, out, nullptr, ROWS, FEAT, FEAT);

    // 5. LN2 -> bf16
    ln_kernel<<<ROWS, blk, 0, stream>>>(out, alpha2, bias2, x2b2);

    // 6. h = ELU(x2b2 @ W1 + b1)
    mfma_gemm<1, 0, 1, 64, 8, 0><<<512, blk, 0, stream>>>(
        x2b2, W1t, b1p, nullptr, hbuf, nullptr, ROWS, FFP, FEAT);

    // 7. out += h @ W2 + b2
    mfma_gemm<0, 1, 0, 128, 8, 0><<<512, blk, 0, stream>>>(
        hbuf, W2t, b2, out, out, nullptr, ROWS, FEAT, FFP);
}